// Round 13
// baseline (45.790 us; speedup 1.0000x reference)
//
#include <hip/hip_runtime.h>
#include <hip/hip_bf16.h>

// SpatialAttention2D MFMA v12: B=2, C=64, N=4096, 4 heads x d=16, fp32 io.
// vs v11: attention waves now cover 64 q each (4 Q-frags) -> every K/V
// fragment feeds 4 QK + 4 PV MFMAs, halving L2 traffic (256->128 MB) and
// raising per-iter compute above L2 latency. 8-wave blocks (wave = key-eighth
// of 512 keys), grid 8bh x 64qgrp = 512 blocks -> 4096 waves = 4/SIMD.
// Depth-2 register pipeline (v11-verified addressing); epilogue LDS combine.
// qkv_proj byte-identical to r12 (Qt [d][n], Kb [n][d], Vf fragment-ordered).

#define NTOK 4096
#define HD   16
#define BH   8
#define EIGHTH 512             // keys per wave
#define PITERS (EIGHTH/32)     // 16 pair-iters (2 chunks of 16 keys each)

typedef __attribute__((ext_vector_type(4))) short short4v;
typedef __attribute__((ext_vector_type(4))) float float4v;
typedef __attribute__((ext_vector_type(4))) ushort ushort4v;
typedef __attribute__((ext_vector_type(2))) unsigned uint2v;

__device__ __forceinline__ ushort f2bf(float f) {
  unsigned u = __builtin_bit_cast(unsigned, f);
  u += 0x7fffu + ((u >> 16) & 1u);          // round-to-nearest-even
  return (ushort)(u >> 16);
}

__device__ __forceinline__ float fast_exp2(float x) {
#if __has_builtin(__builtin_amdgcn_exp2f)
  return __builtin_amdgcn_exp2f(x);
#else
  return exp2f(x);
#endif
}

// packed f32x4 -> bf16x4 (RNE) via v_cvt_pk_bf16_f32 (v6b-verified form)
__device__ __forceinline__ short4v pack4_bf16(float a, float b, float c, float d) {
  __hip_bfloat162 lo = __float22bfloat162_rn(make_float2(a, b));
  __hip_bfloat162 hi = __float22bfloat162_rn(make_float2(c, d));
  unsigned ulo, uhi;
  __builtin_memcpy(&ulo, &lo, 4);
  __builtin_memcpy(&uhi, &hi, 4);
  uint2v u = { ulo, uhi };
  return __builtin_bit_cast(short4v, u);
}

// ws layout in ushort elements (3 MB total)
// Qt: [bh][d][n] (transposed), Kb: [bh][n][d], Vf: [bh] fragment-ordered:
//   element (d, key) at bh*65536 + (key>>4)*256 + ((key&15)>>2)*64 + d*4 + (key&3)
#define QB_OFF 0
#define KB_OFF ((size_t)BH*NTOK*HD)
#define VT_OFF (2*(size_t)BH*NTOK*HD)

// ---------------------------------------------------------------------------
// Kernel 1: QKV projection (byte-identical to r12).
// ---------------------------------------------------------------------------
__global__ __launch_bounds__(192) void qkv_proj(
    const float* __restrict__ x, const float* __restrict__ w,
    const float* __restrict__ bias, ushort* __restrict__ wsu) {
  const int TOK = 8, TILES = 2;
  int blk = blockIdx.x;            // 512
  int b   = blk >> 8;
  int n00 = (blk & 255) * (TOK*TILES);
  int o   = threadIdx.x;           // 0..191

  float wr[64];
  const float4* w4 = reinterpret_cast<const float4*>(w + o*64);
  #pragma unroll
  for (int i = 0; i < 16; ++i) {
    float4 tt = w4[i];
    wr[4*i+0]=tt.x; wr[4*i+1]=tt.y; wr[4*i+2]=tt.z; wr[4*i+3]=tt.w;
  }
  float bb = bias[o];

  int part = o >> 6;               // 0=q,1=k,2=v
  int oo   = o & 63;
  int h    = oo >> 4;
  int dd   = oo & 15;
  int bh   = b*4 + h;
  const float QSCALE = 0.25f * 1.44269504f;

  ushort* Qt = wsu + QB_OFF;
  ushort* Kb = wsu + KB_OFF;
  ushort* Vf = wsu + VT_OFF;

  __shared__ float4 xs4[64][2];
  const float4* x4 = reinterpret_cast<const float4*>(x);

  #pragma unroll 1
  for (int tile = 0; tile < TILES; ++tile) {
    int n0 = n00 + tile*TOK;
    for (int idx = threadIdx.x; idx < 128; idx += 192) {
      int c = idx >> 1, t4 = idx & 1;
      xs4[c][t4] = x4[((size_t)b*64 + c)*(NTOK/4) + (n0 >> 2) + t4];
    }
    __syncthreads();

    #pragma unroll
    for (int t4 = 0; t4 < 2; ++t4) {
      float a[4] = {bb, bb, bb, bb};
      #pragma unroll
      for (int c = 0; c < 64; ++c) {
        float4 xv = xs4[c][t4];
        float wv = wr[c];
        a[0] = fmaf(xv.x, wv, a[0]);
        a[1] = fmaf(xv.y, wv, a[1]);
        a[2] = fmaf(xv.z, wv, a[2]);
        a[3] = fmaf(xv.w, wv, a[3]);
      }
      if (part == 0) {
        ushort4v vv = { f2bf(a[0]*QSCALE), f2bf(a[1]*QSCALE),
                        f2bf(a[2]*QSCALE), f2bf(a[3]*QSCALE) };
        *(ushort4v*)(Qt + ((size_t)bh*HD + dd)*NTOK + n0 + t4*4) = vv;
      } else if (part == 1) {
        #pragma unroll
        for (int j = 0; j < 4; ++j)
          Kb[((size_t)bh*NTOK + n0 + t4*4 + j)*HD + dd] = f2bf(a[j]);
      } else {
        int m = n0 + t4*4;
        size_t idx = (size_t)bh*NTOK*HD + (m >> 4)*256 + ((m & 15) >> 2)*64 + dd*4;
        ushort4v vv = { f2bf(a[0]), f2bf(a[1]), f2bf(a[2]), f2bf(a[3]) };
        *(ushort4v*)(Vf + idx) = vv;
      }
    }
    __syncthreads();
  }
}

// ---------------------------------------------------------------------------
// Kernel 2: register-direct MFMA flash attention, 64 q/wave, depth-2 pipeline.
// Grid = 8 bh x 64 qgrp(64q) = 512 blocks x 512 threads (8 waves).
// Wave wid = key-eighth (512 keys); all 8 waves cover the SAME 64 q.
// Per pair-iter: 4 coalesced frag loads feed 8 QK MFMA + 32 exp2 + 8 PV MFMA.
// ---------------------------------------------------------------------------
__global__ __launch_bounds__(512, 4) void attn_mfma(
    const ushort* __restrict__ wsu, float* __restrict__ out) {
  const ushort* Qt = wsu + QB_OFF;
  const ushort* Kb = wsu + KB_OFF;
  const ushort* Vt = wsu + VT_OFF;

  int bh   = blockIdx.x >> 6;
  int qgrp = blockIdx.x & 63;
  int tid  = threadIdx.x;
  int wid  = tid >> 6;             // 0..7: key-eighth
  int lane = tid & 63;
  int lr   = lane & 15;
  int g4   = (lane >> 4) << 2;
  int qbase = qgrp*64;

  __shared__ float comb[7][64][20];   // 35.8 KB epilogue combine

  const ushort* Qh = Qt + (size_t)bh*HD*NTOK;                       // [d][n]
  const ushort* Kh = Kb + ((size_t)bh*NTOK + (size_t)wid*EIGHTH)*HD;
  const ushort* Vh = Vt + (size_t)bh*NTOK*HD + (size_t)wid*EIGHTH*HD;

  // Q fragments (B operand): qf[qi]: lane l holds Q[qbase+qi*16+(l&15)][g4..g4+3]
  short4v qf[4];
  #pragma unroll
  for (int qi = 0; qi < 4; ++qi)
    #pragma unroll
    for (int j = 0; j < 4; ++j)
      qf[qi][j] = (short)Qh[(size_t)(g4+j)*NTOK + qbase + qi*16 + lr];

  // per-lane fragment pointers (ushort units); pair-iter i reads i*512 (+256)
  const ushort* kp = Kh + lr*HD + (lane >> 4)*4;
  const ushort* vp = Vh + lane*4;

  float4v ae[4], ao[4];
  float lsum[4];
  #pragma unroll
  for (int qi = 0; qi < 4; ++qi) {
    ae[qi] = (float4v){0.f,0.f,0.f,0.f};
    ao[qi] = (float4v){0.f,0.f,0.f,0.f};
    lsum[qi] = 0.f;
  }

#define ITER(ke, ko, ve, vo)                                                \
  do {                                                                      \
    float4v zero = {0.f,0.f,0.f,0.f};                                       \
    __builtin_amdgcn_s_setprio(1);                                          \
    _Pragma("unroll")                                                       \
    for (int qi = 0; qi < 4; ++qi) {                                        \
      float4v se = __builtin_amdgcn_mfma_f32_16x16x16bf16_1k(ke, qf[qi], zero, 0,0,0); \
      float4v so = __builtin_amdgcn_mfma_f32_16x16x16bf16_1k(ko, qf[qi], zero, 0,0,0); \
      float pe0 = fast_exp2(se[0]), pe1 = fast_exp2(se[1]);                 \
      float pe2 = fast_exp2(se[2]), pe3 = fast_exp2(se[3]);                 \
      float po0 = fast_exp2(so[0]), po1 = fast_exp2(so[1]);                 \
      float po2 = fast_exp2(so[2]), po3 = fast_exp2(so[3]);                 \
      lsum[qi] += (pe0 + pe1) + (pe2 + pe3) + (po0 + po1) + (po2 + po3);    \
      short4v pbe = pack4_bf16(pe0, pe1, pe2, pe3);                         \
      short4v pbo = pack4_bf16(po0, po1, po2, po3);                         \
      ae[qi] = __builtin_amdgcn_mfma_f32_16x16x16bf16_1k(ve, pbe, ae[qi], 0,0,0); \
      ao[qi] = __builtin_amdgcn_mfma_f32_16x16x16bf16_1k(vo, pbo, ao[qi], 0,0,0); \
    }                                                                       \
    __builtin_amdgcn_s_setprio(0);                                          \
  } while (0)

  // prologue: fragments for pair-iters 0 (A) and 1 (B)
  short4v kAe = *(const short4v*)(kp);
  short4v kAo = *(const short4v*)(kp + 256);
  short4v vAe = *(const short4v*)(vp);
  short4v vAo = *(const short4v*)(vp + 256);
  short4v kBe = *(const short4v*)(kp + 512);
  short4v kBo = *(const short4v*)(kp + 768);
  short4v vBe = *(const short4v*)(vp + 512);
  short4v vBo = *(const short4v*)(vp + 768);

  #pragma unroll 2
  for (int it2 = 0; it2 < PITERS/2; ++it2) {
    // prefetch pair-iters 2*it2+2 / 2*it2+3 (benign ws over-read at tail)
    int oA = (2*it2 + 2) * 512;
    int oB = (2*it2 + 3) * 512;
    short4v nkAe = *(const short4v*)(kp + oA);
    short4v nkAo = *(const short4v*)(kp + oA + 256);
    short4v nvAe = *(const short4v*)(vp + oA);
    short4v nvAo = *(const short4v*)(vp + oA + 256);
    short4v nkBe = *(const short4v*)(kp + oB);
    short4v nkBo = *(const short4v*)(kp + oB + 256);
    short4v nvBe = *(const short4v*)(vp + oB);
    short4v nvBo = *(const short4v*)(vp + oB + 256);

    ITER(kAe, kAo, vAe, vAo);
    ITER(kBe, kBo, vBe, vBo);

    kAe = nkAe; kAo = nkAo; vAe = nvAe; vAo = nvAo;
    kBe = nkBe; kBo = nkBo; vBe = nvBe; vBo = nvBo;
  }
#undef ITER

  // combine the 8 eighths: waves 1..7 publish, wave 0 reduces + stores
  if (wid != 0) {
    float* cp = &comb[wid-1][lane][0];
    #pragma unroll
    for (int qi = 0; qi < 4; ++qi) {
      #pragma unroll
      for (int r = 0; r < 4; ++r)
        cp[qi*4 + r] = ae[qi][r] + ao[qi][r];
      cp[16 + qi] = lsum[qi];
    }
  }
  __syncthreads();
  if (wid == 0) {
    float o4[4][4], lt[4];
    #pragma unroll
    for (int qi = 0; qi < 4; ++qi) {
      #pragma unroll
      for (int r = 0; r < 4; ++r) o4[qi][r] = ae[qi][r] + ao[qi][r];
      lt[qi] = lsum[qi];
    }
    #pragma unroll
    for (int wv = 0; wv < 7; ++wv) {
      const float* cp = &comb[wv][lane][0];
      #pragma unroll
      for (int qi = 0; qi < 4; ++qi) {
        #pragma unroll
        for (int r = 0; r < 4; ++r) o4[qi][r] += cp[qi*4 + r];
        lt[qi] += cp[16 + qi];
      }
    }
    int b = bh >> 2, h = bh & 3;
    float* ob = out + ((size_t)(b*64 + h*16 + g4)) * NTOK;
    #pragma unroll
    for (int qi = 0; qi < 4; ++qi) {
      float l = lt[qi];
      l += __shfl_xor(l, 16); l += __shfl_xor(l, 32);
      float inv = 1.0f / l;
      #pragma unroll
      for (int r = 0; r < 4; ++r)
        ob[(size_t)r*NTOK + qbase + qi*16 + lr] = o4[qi][r] * inv;
    }
  }
}

extern "C" void kernel_launch(void* const* d_in, const int* in_sizes, int n_in,
                              void* d_out, int out_size, void* d_ws, size_t ws_size,
                              hipStream_t stream) {
  const float* x    = (const float*)d_in[0];   // (2,64,64,64)
  const float* w    = (const float*)d_in[1];   // (192,64)
  const float* bias = (const float*)d_in[2];   // (192,)
  float* out  = (float*)d_out;                 // (2,64,64,64)
  ushort* wsu = (ushort*)d_ws;                 // 3 MB used (+~18KB over-read pad)

  qkv_proj <<<512, 192, 0, stream>>>(x, w, bias, wsu);
  attn_mfma<<<512, 512, 0, stream>>>(wsu, out);
}